// Round 6
// baseline (250.166 us; speedup 1.0000x reference)
//
#include <hip/hip_runtime.h>
#include <stdint.h>
#include <math.h>

#define NH 16
#define DH 64
#define SEQ 2048
#define DMODEL 1024

typedef short short8 __attribute__((ext_vector_type(8)));
typedef short short4v __attribute__((ext_vector_type(4)));
typedef float f32x4 __attribute__((ext_vector_type(4)));
typedef __bf16 bf16x4 __attribute__((ext_vector_type(4)));

__device__ __forceinline__ short f2bf(float f) {
  __bf16 h = (__bf16)f;
  return __builtin_bit_cast(short, h);
}
__device__ __forceinline__ short4v cvt4(f32x4 v) {
  bf16x4 b = __builtin_convertvector(v, bf16x4);
  return __builtin_bit_cast(short4v, b);
}
__device__ __forceinline__ float fast_exp2(float x) {
#if __has_builtin(__builtin_amdgcn_exp2f)
  return __builtin_amdgcn_exp2f(x);
#else
  return exp2f(x);
#endif
}

typedef const __attribute__((address_space(1))) uint32_t* gp_t;
typedef __attribute__((address_space(3))) uint32_t* lp_t;
__device__ __forceinline__ void async16(const short* g, short* l) {
  __builtin_amdgcn_global_load_lds((gp_t)g, (lp_t)l, 16, 0, 0);
}

// ---- fused prep: x fp32->bf16 | w_in^T bf16 | w_out^T bf16 (one launch) ----
__device__ __forceinline__ void transpose_tile(const float* __restrict__ in,
                                               short* __restrict__ out, int R, int C,
                                               int t, int tilesX, int tid) {
  __shared__ float tile[32][33];
  const int tx = tid & 31, ty = tid >> 5;  // 32 x 8
  const int c0 = (t % tilesX) * 32, r0 = (t / tilesX) * 32;
#pragma unroll
  for (int i = 0; i < 4; ++i)
    tile[ty + i * 8][tx] = in[(size_t)(r0 + ty + i * 8) * C + c0 + tx];
  __syncthreads();
#pragma unroll
  for (int i = 0; i < 4; ++i)
    out[(size_t)(c0 + ty + i * 8) * R + r0 + tx] = f2bf(tile[tx][ty + i * 8]);
}

__global__ void k_prep(const float* __restrict__ x, short* __restrict__ xb,
                       const float* __restrict__ w_in, short* __restrict__ w_in_t,
                       const float* __restrict__ w_out, short* __restrict__ w_out_t) {
  const int tid = threadIdx.x;
  const int blk = blockIdx.x;
  if (blk < 4096) {  // x convert
    const int i = blk * 256 + tid;
    f32x4 v = ((const f32x4*)x)[i];
    ((short4v*)xb)[i] = cvt4(v);
  } else if (blk < 4096 + 3072) {  // w_in [1024,3072] -> [3072,1024]
    transpose_tile(w_in, w_in_t, 1024, 3072, blk - 4096, 96, tid);
  } else {  // w_out [1024,1024] -> transpose
    transpose_tile(w_out, w_out_t, 1024, 1024, blk - 7168, 32, tid);
  }
}

// ---------------- GEMM: C[M,N] = A[M,K=1024] * Bt[N,K]^T + bias ------------
// BK=64: 16 K-iters x 32 MFMA. LDS tiles 128x64, XOR-chunk-swizzled so
// global_load_lds (linear, wave-uniform-base) + conflict-free b128 reads.
template <int MODE>
__launch_bounds__(256, 3)
__global__ void k_gemm(const short* __restrict__ A, const short* __restrict__ Bt,
                       const float* __restrict__ bias, float* __restrict__ Cf,
                       short* __restrict__ qo, short* __restrict__ ko,
                       short* __restrict__ vo) {
  constexpr int KD = 1024;
  __shared__ __align__(16) short As[128 * 64];  // 16 KB
  __shared__ __align__(16) short Bs[128 * 64];  // 16 KB
  const int tid = threadIdx.x;
  const int wave = tid >> 6, lane = tid & 63;
  const int quad = lane >> 4, l16 = lane & 15;
  const int wm = wave >> 1, wn = wave & 1;
  const int tM = blockIdx.y * 128, tN = blockIdx.x * 128;

  const short* pA[4];
  const short* pB[4];
  short* lA[4];
  short* lB[4];
#pragma unroll
  for (int t = 0; t < 4; ++t) {
    const int c = t * 256 + tid;
    const int row = c >> 3, gch = (c & 7) ^ (row & 7);
    pA[t] = A + (size_t)(tM + row) * KD + gch * 8;
    pB[t] = Bt + (size_t)(tN + row) * KD + gch * 8;
    lA[t] = &As[c * 8];
    lB[t] = &Bs[c * 8];
  }

  const int sw = l16 & 7;
  const int col0 = (quad ^ sw) << 3;
  const int col1 = col0 ^ 32;

  f32x4 acc[4][4] = {};

  for (int k0 = 0; k0 < KD; k0 += 64) {
    __syncthreads();
#pragma unroll
    for (int t = 0; t < 4; ++t) {
      async16(pA[t] + k0, lA[t]);
      async16(pB[t] + k0, lB[t]);
    }
    __syncthreads();
#pragma unroll
    for (int kh = 0; kh < 2; ++kh) {
      const int col = kh ? col1 : col0;
      short8 af[4], bfr[4];
#pragma unroll
      for (int i = 0; i < 4; ++i)
        af[i] = *(const short8*)&As[(wm * 64 + i * 16 + l16) * 64 + col];
#pragma unroll
      for (int i = 0; i < 4; ++i)
        bfr[i] = *(const short8*)&Bs[(wn * 64 + i * 16 + l16) * 64 + col];
#pragma unroll
      for (int i = 0; i < 4; ++i)
#pragma unroll
        for (int j = 0; j < 4; ++j)
          acc[i][j] = __builtin_amdgcn_mfma_f32_16x16x32_bf16(af[i], bfr[j], acc[i][j], 0, 0, 0);
    }
  }

  const int rbase = tM + wm * 64 + quad * 4;
#pragma unroll
  for (int i = 0; i < 4; ++i) {
#pragma unroll
    for (int j = 0; j < 4; ++j) {
      const int col = tN + wn * 64 + j * 16 + l16;
      const float bi = bias[col];
      if (MODE == 0) {
        const int which = col >> 10;  // uniform per block
        const int h = (col & 1023) >> 6, d = col & 63;
        if (which == 2) {
          const int row0 = rbase + i * 16;
          const int b = row0 >> 11, li0 = row0 & 2047;
          f32x4 t;
#pragma unroll
          for (int rr = 0; rr < 4; ++rr) t[rr] = acc[i][j][rr] + bi;
          *(short4v*)&vo[(((size_t)(b * NH + h)) * DH + d) * SEQ + li0] = cvt4(t);
        } else {
          short* dst = (which == 0) ? qo : ko;
#pragma unroll
          for (int rr = 0; rr < 4; ++rr) {
            const int row = rbase + i * 16 + rr;
            const int b = row >> 11, li = row & 2047;
            dst[(((size_t)(b * NH + h)) * SEQ + li) * DH + d] = f2bf(acc[i][j][rr] + bi);
          }
        }
      } else {
#pragma unroll
        for (int rr = 0; rr < 4; ++rr) {
          const int row = rbase + i * 16 + rr;
          Cf[(size_t)row * DMODEL + col] = acc[i][j][rr] + bi;
        }
      }
    }
  }
}

// -------- flash attention: barrier-free K-loop, register-direct K/V --------
// 1D grid 1024, LPT: qt = 31-(bx>>5), bh = bx&31. All 4 waves read identical
// K/V fragments -> L1 absorbs duplication. Only LDS use: per-wave P round-
// trip (C-layout -> A/B-layout). lsum via ones-row MFMA (no scalar adds).
__launch_bounds__(256)
__global__ void k_attn(const short* __restrict__ q, const short* __restrict__ k,
                       const short* __restrict__ vt, short* __restrict__ o) {
  __shared__ __align__(16) short Ps[4][16 * 64];  // per-wave P [q][key], swizzled
  const int tid = threadIdx.x;
  const int wave = tid >> 6, lane = tid & 63;
  const int quad = lane >> 4, l16 = lane & 15;
  const int sw = l16 & 7;
  const int qt = 31 - (blockIdx.x >> 5);
  const int bh = blockIdx.x & 31;
  const int h = bh & (NH - 1);
  const size_t base = (size_t)bh * SEQ * DH;
  const float LOG2E = 1.44269504088896f;
  const float slope2 = exp2f(-0.5f * (float)(h + 1)) * LOG2E;
  const float scale2 = 0.125f * LOG2E;
  const float FM = 12.0f;  // fixed softmax max; cancels in O/l exactly

  // Ps swizzle (same as R5): write b64 at chunk (2in+(quad>>1))^sw, read b128
  // at chunk quad^sw -> both conflict-free.
  const int col0 = (quad ^ sw) << 3;
  const int col1 = col0 ^ 32;
  int psoff[4];
#pragma unroll
  for (int in = 0; in < 4; ++in)
    psoff[in] = l16 * 64 + (((2 * in + (quad >> 1)) ^ sw) << 3) + (quad & 1) * 4;
  const int qlim4 = wave * 16 + l16 - 4 * quad;  // diag: keep 16*in+r <= qlim4

  const int q0 = qt * 64;
  const int qrow = q0 + wave * 16 + l16;  // each lane owns ONE q-row
  // Q fragment: direct global (B-operand: lane l16 = q-row, quad*8 = k off)
  const short* qp = q + base + (size_t)qrow * DH + quad * 8;
  const short8 qb0 = *(const short8*)qp;
  const short8 qb1 = *(const short8*)(qp + 32);

  short8 ones;
#pragma unroll
  for (int j = 0; j < 8; ++j) ones[j] = (short)0x3F80;  // bf16 1.0

  f32x4 accO[4] = {};
  f32x4 accL = {};
  const float qoff = -slope2 * (float)qrow - FM + slope2 * (float)(4 * quad);
  float inoff[4];
#pragma unroll
  for (int in = 0; in < 4; ++in)
    inoff[in] = qoff + slope2 * (float)(16 * in);
  const float s64 = slope2 * 64.0f;
  float rc[4];
#pragma unroll
  for (int r = 0; r < 4; ++r) rc[r] = slope2 * (float)r;

  // K frag base: row (kb + 16in + l16), col quad*8  (A-operand, wave-uniform)
  const short* kfb = k + base + (size_t)l16 * DH + quad * 8;
  const short* vfb = vt + base + (size_t)l16 * SEQ + quad * 8;

  auto loadK = [&](int kt, short8* kr) {
    const short* p = kfb + (size_t)(kt * 64) * DH;
#pragma unroll
    for (int in = 0; in < 4; ++in) {
      kr[2 * in] = *(const short8*)(p + (size_t)(in * 16) * DH);
      kr[2 * in + 1] = *(const short8*)(p + (size_t)(in * 16) * DH + 32);
    }
  };

  auto step = [&](int kt, const short8* kr, short8* kn, bool pf) {
    // S^T = K Q^T : lane holds keys 16*in+4*quad+r for q-row l16
    f32x4 s[4];
#pragma unroll
    for (int in = 0; in < 4; ++in) {
      f32x4 t = {};
      t = __builtin_amdgcn_mfma_f32_16x16x32_bf16(kr[2 * in], qb0, t, 0, 0, 0);
      t = __builtin_amdgcn_mfma_f32_16x16x32_bf16(kr[2 * in + 1], qb1, t, 0, 0, 0);
      s[in] = t;
    }
    // V frags for this tile (latency hidden under softmax); K prefetch kt+1
    short8 vr[8];
    {
      const short* p = vfb + kt * 64;
#pragma unroll
      for (int i = 0; i < 4; ++i) {
        vr[2 * i] = *(const short8*)(p + (size_t)(i * 16) * SEQ);
        vr[2 * i + 1] = *(const short8*)(p + (size_t)(i * 16) * SEQ + 32);
      }
    }
    if (pf) loadK(kt + 1, kn);

    if (kt == qt) {  // diagonal: causal mask
#pragma unroll
      for (int in = 0; in < 4; ++in) {
        f32x4 p;
#pragma unroll
        for (int r = 0; r < 4; ++r) {
          float val = fast_exp2(fmaf(s[in][r], scale2, inoff[in] + rc[r]));
          p[r] = (16 * in + r <= qlim4) ? val : 0.f;
        }
        *(short4v*)&Ps[wave][psoff[in]] = cvt4(p);
      }
    } else {
#pragma unroll
      for (int in = 0; in < 4; ++in) {
        f32x4 p;
#pragma unroll
        for (int r = 0; r < 4; ++r)
          p[r] = fast_exp2(fmaf(s[in][r], scale2, inoff[in] + rc[r]));
        *(short4v*)&Ps[wave][psoff[in]] = cvt4(p);
      }
    }
#pragma unroll
    for (int in = 0; in < 4; ++in) inoff[in] += s64;

    // O^T += V^T P^T ; row-sum via ones-row MFMA (all C rows = lsum[q])
    const short8 pa0 = *(const short8*)&Ps[wave][l16 * 64 + col0];
    const short8 pa1 = *(const short8*)&Ps[wave][l16 * 64 + col1];
    accL = __builtin_amdgcn_mfma_f32_16x16x32_bf16(ones, pa0, accL, 0, 0, 0);
    accL = __builtin_amdgcn_mfma_f32_16x16x32_bf16(ones, pa1, accL, 0, 0, 0);
#pragma unroll
    for (int i = 0; i < 4; ++i) {
      accO[i] = __builtin_amdgcn_mfma_f32_16x16x32_bf16(vr[2 * i], pa0, accO[i], 0, 0, 0);
      accO[i] = __builtin_amdgcn_mfma_f32_16x16x32_bf16(vr[2 * i + 1], pa1, accO[i], 0, 0, 0);
    }
  };

  short8 kA[8], kB[8];
  loadK(0, kA);
  int kt = 0;
  for (;;) {
    step(kt, kA, kB, kt < qt);
    if (++kt > qt) break;
    step(kt, kB, kA, kt < qt);
    if (++kt > qt) break;
  }

  const float inv = 1.0f / accL[0];
  const int b = bh >> 4;
  short* ob = o + ((((size_t)b * SEQ + qrow) * NH + h) * DH + 4 * quad);
#pragma unroll
  for (int i = 0; i < 4; ++i) {
    f32x4 t;
#pragma unroll
    for (int r = 0; r < 4; ++r) t[r] = accO[i][r] * inv;
    *(short4v*)&ob[16 * i] = cvt4(t);
  }
}

extern "C" void kernel_launch(void* const* d_in, const int* in_sizes, int n_in,
                              void* d_out, int out_size, void* d_ws, size_t ws_size,
                              hipStream_t stream) {
  const float* x = (const float*)d_in[0];      // [2,2048,1024]
  const float* w_in = (const float*)d_in[1];   // [1024,3072]
  const float* b_in = (const float*)d_in[2];   // [3072]
  const float* w_out = (const float*)d_in[3];  // [1024,1024]
  const float* b_out = (const float*)d_in[4];  // [1024]
  float* out = (float*)d_out;

  char* ws = (char*)d_ws;
  short* xb = (short*)(ws);                     // 8 MB  bf16 x
  short* w_in_t = (short*)(ws + (8u << 20));    // 6 MB  bf16 w_in^T [3072][1024]
  short* w_out_t = (short*)(ws + (14u << 20));  // 2 MB  bf16 w_out^T
  short* qv = (short*)(ws + (16u << 20));       // 8 MB  [B,H,L,dh]
  short* kv = (short*)(ws + (24u << 20));       // 8 MB  [B,H,L,dh]
  short* vv = (short*)(ws + (32u << 20));       // 8 MB  [B,H,dh,L] (transposed)
  short* ao = (short*)(ws + (40u << 20));       // 8 MB  attn out [B,L,D] bf16

  k_prep<<<8192, 256, 0, stream>>>(x, xb, w_in, w_in_t, w_out, w_out_t);
  k_gemm<0><<<dim3(24, 32), 256, 0, stream>>>(xb, w_in_t, b_in, nullptr, qv, kv, vv);
  k_attn<<<1024, 256, 0, stream>>>(qv, kv, vv, ao);
  k_gemm<1><<<dim3(8, 32), 256, 0, stream>>>(ao, w_out_t, b_out, out, nullptr, nullptr, nullptr);
}

// Round 7
// 169.106 us; speedup vs baseline: 1.4793x; 1.4793x over previous
//
#include <hip/hip_runtime.h>
#include <stdint.h>
#include <math.h>

#define NH 16
#define DH 64
#define SEQ 2048
#define DMODEL 1024

typedef short short8 __attribute__((ext_vector_type(8)));
typedef short short4v __attribute__((ext_vector_type(4)));
typedef float f32x4 __attribute__((ext_vector_type(4)));
typedef __bf16 bf16x4 __attribute__((ext_vector_type(4)));

__device__ __forceinline__ short f2bf(float f) {
  __bf16 h = (__bf16)f;
  return __builtin_bit_cast(short, h);
}
__device__ __forceinline__ short4v cvt4(f32x4 v) {
  bf16x4 b = __builtin_convertvector(v, bf16x4);
  return __builtin_bit_cast(short4v, b);
}
__device__ __forceinline__ float fast_exp2(float x) {
#if __has_builtin(__builtin_amdgcn_exp2f)
  return __builtin_amdgcn_exp2f(x);
#else
  return exp2f(x);
#endif
}

typedef const __attribute__((address_space(1))) uint32_t* gp_t;
typedef __attribute__((address_space(3))) uint32_t* lp_t;
__device__ __forceinline__ void async16(const short* g, short* l) {
  __builtin_amdgcn_global_load_lds((gp_t)g, (lp_t)l, 16, 0, 0);
}

// ---- fused prep: x fp32->bf16 | w_in^T bf16 | w_out^T bf16 (one launch) ----
__device__ __forceinline__ void transpose_tile(const float* __restrict__ in,
                                               short* __restrict__ out, int R, int C,
                                               int t, int tilesX, int tid) {
  __shared__ float tile[32][33];
  const int tx = tid & 31, ty = tid >> 5;  // 32 x 8
  const int c0 = (t % tilesX) * 32, r0 = (t / tilesX) * 32;
#pragma unroll
  for (int i = 0; i < 4; ++i)
    tile[ty + i * 8][tx] = in[(size_t)(r0 + ty + i * 8) * C + c0 + tx];
  __syncthreads();
#pragma unroll
  for (int i = 0; i < 4; ++i)
    out[(size_t)(c0 + ty + i * 8) * R + r0 + tx] = f2bf(tile[tx][ty + i * 8]);
}

__global__ void k_prep(const float* __restrict__ x, short* __restrict__ xb,
                       const float* __restrict__ w_in, short* __restrict__ w_in_t,
                       const float* __restrict__ w_out, short* __restrict__ w_out_t) {
  const int tid = threadIdx.x;
  const int blk = blockIdx.x;
  if (blk < 4096) {  // x convert
    const int i = blk * 256 + tid;
    f32x4 v = ((const f32x4*)x)[i];
    ((short4v*)xb)[i] = cvt4(v);
  } else if (blk < 4096 + 3072) {  // w_in [1024,3072] -> [3072,1024]
    transpose_tile(w_in, w_in_t, 1024, 3072, blk - 4096, 96, tid);
  } else {  // w_out [1024,1024] -> transpose
    transpose_tile(w_out, w_out_t, 1024, 1024, blk - 7168, 32, tid);
  }
}

// ---------------- GEMM: C[M,N] = A[M,K=1024] * Bt[N,K]^T + bias ------------
// BK=64: 16 K-iters x 32 MFMA. LDS tiles 128x64, XOR-chunk-swizzled so
// global_load_lds (linear, wave-uniform-base) + conflict-free b128 reads.
template <int MODE>
__launch_bounds__(256, 3)
__global__ void k_gemm(const short* __restrict__ A, const short* __restrict__ Bt,
                       const float* __restrict__ bias, float* __restrict__ Cf,
                       short* __restrict__ qo, short* __restrict__ ko,
                       short* __restrict__ vo) {
  constexpr int KD = 1024;
  __shared__ __align__(16) short As[128 * 64];  // 16 KB
  __shared__ __align__(16) short Bs[128 * 64];  // 16 KB
  const int tid = threadIdx.x;
  const int wave = tid >> 6, lane = tid & 63;
  const int quad = lane >> 4, l16 = lane & 15;
  const int wm = wave >> 1, wn = wave & 1;
  const int tM = blockIdx.y * 128, tN = blockIdx.x * 128;

  const short* pA[4];
  const short* pB[4];
  short* lA[4];
  short* lB[4];
#pragma unroll
  for (int t = 0; t < 4; ++t) {
    const int c = t * 256 + tid;
    const int row = c >> 3, gch = (c & 7) ^ (row & 7);
    pA[t] = A + (size_t)(tM + row) * KD + gch * 8;
    pB[t] = Bt + (size_t)(tN + row) * KD + gch * 8;
    lA[t] = &As[c * 8];
    lB[t] = &Bs[c * 8];
  }

  const int sw = l16 & 7;
  const int col0 = (quad ^ sw) << 3;
  const int col1 = col0 ^ 32;

  f32x4 acc[4][4] = {};

  for (int k0 = 0; k0 < KD; k0 += 64) {
    __syncthreads();
#pragma unroll
    for (int t = 0; t < 4; ++t) {
      async16(pA[t] + k0, lA[t]);
      async16(pB[t] + k0, lB[t]);
    }
    __syncthreads();
#pragma unroll
    for (int kh = 0; kh < 2; ++kh) {
      const int col = kh ? col1 : col0;
      short8 af[4], bfr[4];
#pragma unroll
      for (int i = 0; i < 4; ++i)
        af[i] = *(const short8*)&As[(wm * 64 + i * 16 + l16) * 64 + col];
#pragma unroll
      for (int i = 0; i < 4; ++i)
        bfr[i] = *(const short8*)&Bs[(wn * 64 + i * 16 + l16) * 64 + col];
#pragma unroll
      for (int i = 0; i < 4; ++i)
#pragma unroll
        for (int j = 0; j < 4; ++j)
          acc[i][j] = __builtin_amdgcn_mfma_f32_16x16x32_bf16(af[i], bfr[j], acc[i][j], 0, 0, 0);
    }
  }

  const int rbase = tM + wm * 64 + quad * 4;
#pragma unroll
  for (int i = 0; i < 4; ++i) {
#pragma unroll
    for (int j = 0; j < 4; ++j) {
      const int col = tN + wn * 64 + j * 16 + l16;
      const float bi = bias[col];
      if (MODE == 0) {
        const int which = col >> 10;  // uniform per block
        const int h = (col & 1023) >> 6, d = col & 63;
        if (which == 2) {
          const int row0 = rbase + i * 16;
          const int b = row0 >> 11, li0 = row0 & 2047;
          f32x4 t;
#pragma unroll
          for (int rr = 0; rr < 4; ++rr) t[rr] = acc[i][j][rr] + bi;
          *(short4v*)&vo[(((size_t)(b * NH + h)) * DH + d) * SEQ + li0] = cvt4(t);
        } else {
          short* dst = (which == 0) ? qo : ko;
#pragma unroll
          for (int rr = 0; rr < 4; ++rr) {
            const int row = rbase + i * 16 + rr;
            const int b = row >> 11, li = row & 2047;
            dst[(((size_t)(b * NH + h)) * SEQ + li) * DH + d] = f2bf(acc[i][j][rr] + bi);
          }
        }
      } else {
#pragma unroll
        for (int rr = 0; rr < 4; ++rr) {
          const int row = rbase + i * 16 + rr;
          Cf[(size_t)row * DMODEL + col] = acc[i][j][rr] + bi;
        }
      }
    }
  }
}

// -------- flash attention: LDS-staged K/V, double-buffered, 1 barrier/tile -
// 1D grid 1024, LPT: qt = 31-(bx>>5), bh = bx&31. Prefetch tile kt+1 via
// global_load_lds BEFORE computing tile kt; the barrier's vmcnt drain then
// lands after compute has covered the latency. Q frags direct from global
// (one-time). lsum via ones-row MFMA.
__launch_bounds__(256)
__global__ void k_attn(const short* __restrict__ q, const short* __restrict__ k,
                       const short* __restrict__ vt, short* __restrict__ o) {
  __shared__ __align__(16) short Ks[2][64 * 64];  // 2 x 8 KB
  __shared__ __align__(16) short Vs[2][64 * 64];  // 2 x 8 KB, V^T tile [d][key]
  __shared__ __align__(16) short Ps[4][16 * 64];  // per-wave P [q][key], swizzled
  const int tid = threadIdx.x;
  const int wave = tid >> 6, lane = tid & 63;
  const int quad = lane >> 4, l16 = lane & 15;
  const int sw = l16 & 7;
  const int qt = 31 - (blockIdx.x >> 5);
  const int bh = blockIdx.x & 31;
  const int h = bh & (NH - 1);
  const size_t base = (size_t)bh * SEQ * DH;
  const float LOG2E = 1.44269504088896f;
  const float slope2 = exp2f(-0.5f * (float)(h + 1)) * LOG2E;
  const float scale2 = 0.125f * LOG2E;
  const float FM = 12.0f;  // fixed softmax max; cancels in O/l exactly

  // staging chunks: c = t*256+tid, row=c>>3, ch=(c&7)^(row&7); lds off = c*16B
  const int c0i = tid, c1i = 256 + tid;
  const int r0 = c0i >> 3, ch0 = (c0i & 7) ^ (r0 & 7);
  const int r1 = c1i >> 3, ch1 = (c1i & 7) ^ (r1 & 7);
  const int qk_off0 = r0 * DH + ch0 * 8;
  const int qk_off1 = r1 * DH + ch1 * 8;
  const int v_off0 = r0 * SEQ + ch0 * 8;
  const int v_off1 = r1 * SEQ + ch1 * 8;

  // frag read columns (swizzled)
  const int col0 = ((quad ^ sw) << 3);
  const int col1 = col0 ^ 32;
  int psoff[4];
#pragma unroll
  for (int in = 0; in < 4; ++in)
    psoff[in] = l16 * 64 + (((2 * in + (quad >> 1)) ^ sw) << 3) + (quad & 1) * 4;
  const int qlim4 = wave * 16 + l16 - 4 * quad;  // diag: keep 16*in+r <= qlim4

  const int q0 = qt * 64;
  const int qrow = q0 + wave * 16 + l16;  // each lane owns ONE q-row
  // Q fragment: direct global one-time load (B-operand layout)
  const short* qp = q + base + (size_t)qrow * DH + quad * 8;
  const short8 qb0 = *(const short8*)qp;
  const short8 qb1 = *(const short8*)(qp + 32);

  short8 ones;
#pragma unroll
  for (int j = 0; j < 8; ++j) ones[j] = (short)0x3F80;  // bf16 1.0

  f32x4 accO[4] = {};
  f32x4 accL = {};
  const float qoff = -slope2 * (float)qrow - FM + slope2 * (float)(4 * quad);
  float inoff[4];
#pragma unroll
  for (int in = 0; in < 4; ++in)
    inoff[in] = qoff + slope2 * (float)(16 * in);
  const float s64 = slope2 * 64.0f;
  float rc[4];
#pragma unroll
  for (int r = 0; r < 4; ++r) rc[r] = slope2 * (float)r;

  const short* kp = k + base;   // advances 64 rows per tile
  const short* vp = vt + base;  // advances 64 cols per tile

  // stage tile 0 into buf 0
  async16(kp + qk_off0, &Ks[0][c0i * 8]);
  async16(kp + qk_off1, &Ks[0][c1i * 8]);
  async16(vp + v_off0, &Vs[0][c0i * 8]);
  async16(vp + v_off1, &Vs[0][c1i * 8]);
  kp += 64 * DH;
  vp += 64;
  __syncthreads();

  for (int kt = 0; kt <= qt; ++kt) {
    const int cur = kt & 1, nxt = cur ^ 1;
    if (kt < qt) {  // prefetch kt+1 BEFORE compute; barrier drains it after
      async16(kp + qk_off0, &Ks[nxt][c0i * 8]);
      async16(kp + qk_off1, &Ks[nxt][c1i * 8]);
      async16(vp + v_off0, &Vs[nxt][c0i * 8]);
      async16(vp + v_off1, &Vs[nxt][c1i * 8]);
      kp += 64 * DH;
      vp += 64;
    }

    // S^T = K Q^T : lane holds keys 16*in+4*quad+r for q-row l16
    f32x4 s[4];
#pragma unroll
    for (int in = 0; in < 4; ++in) {
      const short8 ka0 = *(const short8*)&Ks[cur][(in * 16 + l16) * 64 + col0];
      const short8 ka1 = *(const short8*)&Ks[cur][(in * 16 + l16) * 64 + col1];
      f32x4 t = {};
      t = __builtin_amdgcn_mfma_f32_16x16x32_bf16(ka0, qb0, t, 0, 0, 0);
      t = __builtin_amdgcn_mfma_f32_16x16x32_bf16(ka1, qb1, t, 0, 0, 0);
      s[in] = t;
    }

    if (kt == qt) {  // diagonal: causal mask
#pragma unroll
      for (int in = 0; in < 4; ++in) {
        f32x4 p;
#pragma unroll
        for (int r = 0; r < 4; ++r) {
          float val = fast_exp2(fmaf(s[in][r], scale2, inoff[in] + rc[r]));
          p[r] = (16 * in + r <= qlim4) ? val : 0.f;
        }
        *(short4v*)&Ps[wave][psoff[in]] = cvt4(p);
      }
    } else {
#pragma unroll
      for (int in = 0; in < 4; ++in) {
        f32x4 p;
#pragma unroll
        for (int r = 0; r < 4; ++r)
          p[r] = fast_exp2(fmaf(s[in][r], scale2, inoff[in] + rc[r]));
        *(short4v*)&Ps[wave][psoff[in]] = cvt4(p);
      }
    }
#pragma unroll
    for (int in = 0; in < 4; ++in) inoff[in] += s64;

    // O^T += V^T P^T ; row-sum via ones-row MFMA
    const short8 pa0 = *(const short8*)&Ps[wave][l16 * 64 + col0];
    const short8 pa1 = *(const short8*)&Ps[wave][l16 * 64 + col1];
    accL = __builtin_amdgcn_mfma_f32_16x16x32_bf16(ones, pa0, accL, 0, 0, 0);
    accL = __builtin_amdgcn_mfma_f32_16x16x32_bf16(ones, pa1, accL, 0, 0, 0);
#pragma unroll
    for (int i = 0; i < 4; ++i) {
      const short8 va0 = *(const short8*)&Vs[cur][(i * 16 + l16) * 64 + col0];
      const short8 va1 = *(const short8*)&Vs[cur][(i * 16 + l16) * 64 + col1];
      accO[i] = __builtin_amdgcn_mfma_f32_16x16x32_bf16(va0, pa0, accO[i], 0, 0, 0);
      accO[i] = __builtin_amdgcn_mfma_f32_16x16x32_bf16(va1, pa1, accO[i], 0, 0, 0);
    }
    __syncthreads();  // publishes buf[nxt] (prefetch) + frees buf[cur]
  }

  const float inv = 1.0f / accL[0];
  const int b = bh >> 4;
  short* ob = o + ((((size_t)b * SEQ + qrow) * NH + h) * DH + 4 * quad);
#pragma unroll
  for (int i = 0; i < 4; ++i) {
    f32x4 t;
#pragma unroll
    for (int r = 0; r < 4; ++r) t[r] = accO[i][r] * inv;
    *(short4v*)&ob[16 * i] = cvt4(t);
  }
}

extern "C" void kernel_launch(void* const* d_in, const int* in_sizes, int n_in,
                              void* d_out, int out_size, void* d_ws, size_t ws_size,
                              hipStream_t stream) {
  const float* x = (const float*)d_in[0];      // [2,2048,1024]
  const float* w_in = (const float*)d_in[1];   // [1024,3072]
  const float* b_in = (const float*)d_in[2];   // [3072]
  const float* w_out = (const float*)d_in[3];  // [1024,1024]
  const float* b_out = (const float*)d_in[4];  // [1024]
  float* out = (float*)d_out;

  char* ws = (char*)d_ws;
  short* xb = (short*)(ws);                     // 8 MB  bf16 x
  short* w_in_t = (short*)(ws + (8u << 20));    // 6 MB  bf16 w_in^T [3072][1024]
  short* w_out_t = (short*)(ws + (14u << 20));  // 2 MB  bf16 w_out^T
  short* qv = (short*)(ws + (16u << 20));       // 8 MB  [B,H,L,dh]
  short* kv = (short*)(ws + (24u << 20));       // 8 MB  [B,H,L,dh]
  short* vv = (short*)(ws + (32u << 20));       // 8 MB  [B,H,dh,L] (transposed)
  short* ao = (short*)(ws + (40u << 20));       // 8 MB  attn out [B,L,D] bf16

  k_prep<<<8192, 256, 0, stream>>>(x, xb, w_in, w_in_t, w_out, w_out_t);
  k_gemm<0><<<dim3(24, 32), 256, 0, stream>>>(xb, w_in_t, b_in, nullptr, qv, kv, vv);
  k_attn<<<1024, 256, 0, stream>>>(qv, kv, vv, ao);
  k_gemm<1><<<dim3(8, 32), 256, 0, stream>>>(ao, w_out_t, b_out, out, nullptr, nullptr, nullptr);
}